// Round 4
// baseline (280.419 us; speedup 1.0000x reference)
//
#include <hip/hip_runtime.h>
#include <hip/hip_bf16.h>

#define Bn  512
#define DXn 128
#define Hn  512

using bf16x8 = __attribute__((ext_vector_type(8))) short;
using f32x16 = __attribute__((ext_vector_type(16))) float;

// packed f32x2 -> bf16x2 (RNE); compiler emits v_cvt_pk_bf16_f32
static __device__ __forceinline__ unsigned int pkbf(float lo, float hi) {
    union { __hip_bfloat162 b; unsigned int u; } cv;
    cv.b = __float22bfloat162_rn(make_float2(lo, hi));
    return cv.u;
}

// ---------------------------------------------------------------------------
// Fused prep kernel:
//  blocks 0..255   : hxb[i][h] = x·W1x^T + b1 / hyv[j][h] = y·W1y^T
//  blocks 256..383 : W2 f32 -> bf16 32x32-fragment-ordered:
//     w2s[kf2][s][lane][8], elem = W2[kf2*32 + (l&31)][s*16 + (l>>5)*8 + j]
// ---------------------------------------------------------------------------
__global__ __launch_bounds__(256) void prep_fused(
    const float* __restrict__ x, const float* __restrict__ y,
    const float* __restrict__ W1, const float* __restrict__ b1,
    const float* __restrict__ W2,
    float* __restrict__ hxb, float* __restrict__ hyv,
    unsigned short* __restrict__ w2s)
{
    const int bid = blockIdx.x;
    const int t = threadIdx.x;

    if (bid >= 256) {
        const int T = (bid - 256) * 256 + t;        // 0 .. 32767
        const int l   = T & 63;
        const int s   = (T >> 6) & 31;
        const int kf2 = T >> 11;
        const int row = kf2 * 32 + (l & 31);
        const int col = s * 16 + (l >> 5) * 8;
        const float* p = &W2[row * Hn + col];
        const float4 v0 = *(const float4*)p;
        const float4 v1 = *(const float4*)(p + 4);
        uint4 pk;
        pk.x = pkbf(v0.x, v0.y);
        pk.y = pkbf(v0.z, v0.w);
        pk.z = pkbf(v1.x, v1.y);
        pk.w = pkbf(v1.z, v1.w);
        *(uint4*)(w2s + (size_t)T * 8) = pk;
        return;
    }

    // ---- first-layer GEMM: 32 i x 64 h per block, 8 outputs/thread ----
    const int which = bid >> 7;
    const int rem = bid & 127;
    const int i0 = (rem >> 3) * 32;
    const int h0 = (rem & 7) * 64;
    const float* __restrict__ src = which ? y : x;
    float* __restrict__ dst = which ? hyv : hxb;
    const int off = which ? DXn : 0;

    __shared__ float xs[32][132];
    __shared__ float ws[64][132];
    #pragma unroll
    for (int it = 0; it < 4; ++it) {
        const int fi = it * 256 + t;
        const int r = fi >> 5, q = fi & 31;
        *(float4*)&xs[r][q * 4] = *(const float4*)&src[(i0 + r) * DXn + q * 4];
    }
    #pragma unroll
    for (int it = 0; it < 8; ++it) {
        const int fi = it * 256 + t;
        const int r = fi >> 5, q = fi & 31;
        *(float4*)&ws[r][q * 4] = *(const float4*)&W1[(h0 + r) * (2 * DXn) + off + q * 4];
    }
    __syncthreads();

    const int tx = t & 15;
    const int ty = t >> 4;
    float acc[2][4];
    #pragma unroll
    for (int v = 0; v < 2; ++v)
        #pragma unroll
        for (int u = 0; u < 4; ++u)
            acc[v][u] = which ? 0.0f : b1[h0 + tx + u * 16];

    #pragma unroll 4
    for (int c4 = 0; c4 < 32; ++c4) {
        const float4 xv0 = *(const float4*)&xs[ty * 2 + 0][c4 * 4];
        const float4 xv1 = *(const float4*)&xs[ty * 2 + 1][c4 * 4];
        #pragma unroll
        for (int u = 0; u < 4; ++u) {
            const float4 wv = *(const float4*)&ws[tx + u * 16][c4 * 4];
            acc[0][u] = fmaf(xv0.x, wv.x, fmaf(xv0.y, wv.y, fmaf(xv0.z, wv.z, fmaf(xv0.w, wv.w, acc[0][u]))));
            acc[1][u] = fmaf(xv1.x, wv.x, fmaf(xv1.y, wv.y, fmaf(xv1.z, wv.z, fmaf(xv1.w, wv.w, acc[1][u]))));
        }
    }
    #pragma unroll
    for (int v = 0; v < 2; ++v)
        #pragma unroll
        for (int u = 0; u < 4; ++u)
            dst[(size_t)(i0 + ty * 2 + v) * Hn + h0 + tx + u * 16] = acc[v][u];
}

// ---------------------------------------------------------------------------
// Main fused kernel, 32x32x16 MFMA version.
// Block = (one i, 128 consecutive j's), 8 waves, 1 block/CU (128KB LDS).
//   A[r][h] = relu(hxb[i][h] + hyv[j0+r][h]) staged bf16 in LDS, frag order:
//     a_lds[rf 4][s 32][lane 64][8], elem = A[rf*32+(l&31)][s*16+(l>>5)*8+j]
//   Wave w: all 128 rows (fi=0..3, 32-row frags) x k in [64w, 64w+64) (fj=0..1).
//   acc = 4x2 f32x16 = 128 regs; A and B double-buffered one k-step ahead
//   (~258 SIMD-cyc > L2 ~200 > LDS ~120 latency).
//   out[i][j0+r] = sum_k relu(C[r][k] + b2[k]) * W3[k] + b3
// ---------------------------------------------------------------------------
__global__ __launch_bounds__(512, 2) void critic_main(
    const float* __restrict__ hxb, const float* __restrict__ hyv,
    const unsigned short* __restrict__ w2s, const float* __restrict__ b2,
    const float* __restrict__ W3, const float* __restrict__ b3,
    float* __restrict__ out)
{
    __shared__ __align__(16) unsigned char smem[131072];
    unsigned short* a_lds = (unsigned short*)smem;  // [4][32][64][8] bf16
    float* red = (float*)smem;                      // reused after MFMA: [16][128]

    const int i   = blockIdx.y;
    const int j0  = blockIdx.x * 128;
    const int tid = threadIdx.x;
    const int w   = tid >> 6;
    const int l   = tid & 63;
    const int l5  = l >> 5;      // k-half within fragment
    const int lc  = l & 31;      // row/col within fragment

    // ---- stage A tile (128 rows x 512 h, bf16, 32x32-frag order) ----
    // wave w: rowfrag rf = w&3, steps s = (w>>2)*16 + q, q=0..15
    {
        const int rf = w & 3;
        const int sb = (w >> 2) * 16;
        const int r  = rf * 32 + lc;
        const float* __restrict__ hyrow = &hyv[(size_t)(j0 + r) * Hn];
        const float* __restrict__ hxrow = &hxb[(size_t)i * Hn];
        #pragma unroll
        for (int q = 0; q < 16; ++q) {
            const int s  = sb + q;
            const int h0 = s * 16 + l5 * 8;
            const float4 a0 = *(const float4*)(hyrow + h0);
            const float4 a1 = *(const float4*)(hyrow + h0 + 4);
            const float4 x0 = *(const float4*)(hxrow + h0);
            const float4 x1 = *(const float4*)(hxrow + h0 + 4);
            uint4 pk;
            pk.x = pkbf(fmaxf(a0.x + x0.x, 0.f), fmaxf(a0.y + x0.y, 0.f));
            pk.y = pkbf(fmaxf(a0.z + x0.z, 0.f), fmaxf(a0.w + x0.w, 0.f));
            pk.z = pkbf(fmaxf(a1.x + x1.x, 0.f), fmaxf(a1.y + x1.y, 0.f));
            pk.w = pkbf(fmaxf(a1.z + x1.z, 0.f), fmaxf(a1.w + x1.w, 0.f));
            *(uint4*)(a_lds + ((size_t)(rf * 32 + s) * 64 + l) * 8) = pk;
        }
    }
    __syncthreads();

    // ---- GEMM: 32 k-steps (K=16), 8 MFMA each (4 fi x 2 fj) ----
    f32x16 acc[4][2] = {};
    const unsigned short* __restrict__ wbase =
        w2s + (size_t)(w * 2) * 32 * 64 * 8;   // kf2 = w*2, w*2+1

    bf16x8 a[2][4], b[2][2];
    #pragma unroll
    for (int fi = 0; fi < 4; ++fi)
        a[0][fi] = *(const bf16x8*)(a_lds + ((size_t)(fi * 32) * 64 + l) * 8);
    #pragma unroll
    for (int fj = 0; fj < 2; ++fj)
        b[0][fj] = *(const bf16x8*)(wbase + ((size_t)(fj * 32) * 64 + l) * 8);

    #pragma unroll
    for (int s = 0; s < 32; ++s) {
        const int cur = s & 1, nxt = cur ^ 1;
        if (s < 31) {   // prefetch next step (compile-time guard, full unroll)
            #pragma unroll
            for (int fj = 0; fj < 2; ++fj)
                b[nxt][fj] = *(const bf16x8*)(wbase + ((size_t)(fj * 32 + s + 1) * 64 + l) * 8);
            #pragma unroll
            for (int fi = 0; fi < 4; ++fi)
                a[nxt][fi] = *(const bf16x8*)(a_lds + ((size_t)(fi * 32 + s + 1) * 64 + l) * 8);
        }
        __builtin_amdgcn_s_setprio(1);
        #pragma unroll
        for (int fi = 0; fi < 4; ++fi)
            #pragma unroll
            for (int fj = 0; fj < 2; ++fj)
                acc[fi][fj] = __builtin_amdgcn_mfma_f32_32x32x16_bf16(
                    a[cur][fi], b[cur][fj], acc[fi][fj], 0, 0, 0);
        __builtin_amdgcn_s_setprio(0);
    }

    // ---- epilogue: relu(C + b2)*W3, reduce over k ----
    // C/D layout: col = lc (k within frag), row = (q&3) + 8*(q>>2) + 4*l5
    float b2v[2], w3v[2];
    #pragma unroll
    for (int fj = 0; fj < 2; ++fj) {
        const int k = w * 64 + fj * 32 + lc;
        b2v[fj] = b2[k];
        w3v[fj] = W3[k];
    }
    float rp[4][16];
    #pragma unroll
    for (int fi = 0; fi < 4; ++fi) {
        #pragma unroll
        for (int q = 0; q < 16; ++q) {
            float ssum = 0.f;
            #pragma unroll
            for (int fj = 0; fj < 2; ++fj) {
                float c = acc[fi][fj][q] + b2v[fj];
                c = fmaxf(c, 0.f);
                ssum = fmaf(c, w3v[fj], ssum);
            }
            rp[fi][q] = ssum;
        }
    }
    // reduce over k-lanes: 4 rounds within 16-lane groups; the 16-vs-16 and
    // cross-wave sums are folded into the final LDS pass.
    #pragma unroll
    for (int m = 1; m < 16; m <<= 1) {
        #pragma unroll
        for (int fi = 0; fi < 4; ++fi)
            #pragma unroll
            for (int q = 0; q < 16; ++q)
                rp[fi][q] += __shfl_xor(rp[fi][q], m, 64);
    }

    __syncthreads();   // all waves done with a_lds; safe to reuse as red[]
    if ((l & 15) == 0) {
        const int half = (l >> 4) & 1;          // which 16-lane k-subgroup
        #pragma unroll
        for (int fi = 0; fi < 4; ++fi)
            #pragma unroll
            for (int q = 0; q < 16; ++q) {
                const int row = (q & 3) + 8 * (q >> 2) + 4 * l5;
                red[(w * 2 + half) * 128 + fi * 32 + row] = rp[fi][q];
            }
    }
    __syncthreads();
    if (tid < 128) {
        float ssum = 0.f;
        #pragma unroll
        for (int p = 0; p < 16; ++p) ssum += red[p * 128 + tid];
        out[(size_t)i * Bn + j0 + tid] = ssum + b3[0];
    }
}

// ---------------------------------------------------------------------------
extern "C" void kernel_launch(void* const* d_in, const int* in_sizes, int n_in,
                              void* d_out, int out_size, void* d_ws, size_t ws_size,
                              hipStream_t stream) {
    const float* x  = (const float*)d_in[0];
    const float* y  = (const float*)d_in[1];
    const float* W1 = (const float*)d_in[2];
    const float* b1 = (const float*)d_in[3];
    const float* W2 = (const float*)d_in[4];
    const float* b2 = (const float*)d_in[5];
    const float* W3 = (const float*)d_in[6];
    const float* b3 = (const float*)d_in[7];
    float* out = (float*)d_out;

    char* ws = (char*)d_ws;
    float* hxb = (float*)ws;                                   // 1 MB
    float* hyv = (float*)(ws + (size_t)Bn * Hn * 4);           // 1 MB
    unsigned short* w2s = (unsigned short*)(ws + (size_t)2 * Bn * Hn * 4); // 512 KB

    prep_fused<<<dim3(384), dim3(256), 0, stream>>>(x, y, W1, b1, W2, hxb, hyv, w2s);
    critic_main<<<dim3(Bn / 128, Bn), dim3(512), 0, stream>>>(hxb, hyv, w2s, b2, W3, b3, out);
}

// Round 5
// 263.211 us; speedup vs baseline: 1.0654x; 1.0654x over previous
//
#include <hip/hip_runtime.h>
#include <hip/hip_bf16.h>

#define Bn  512
#define DXn 128
#define Hn  512

using bf16x8 = __attribute__((ext_vector_type(8))) short;
using f32x4  = __attribute__((ext_vector_type(4))) float;

// packed f32x2 -> bf16x2 (RNE); compiler emits v_cvt_pk_bf16_f32
static __device__ __forceinline__ unsigned int pkbf(float lo, float hi) {
    union { __hip_bfloat162 b; unsigned int u; } cv;
    cv.b = __float22bfloat162_rn(make_float2(lo, hi));
    return cv.u;
}

// async global->LDS, 16B per lane; LDS dest = wave-uniform base + lane*16
static __device__ __forceinline__ void gld_lds16(const void* g, void* l) {
    __builtin_amdgcn_global_load_lds(
        (const __attribute__((address_space(1))) unsigned int*)g,
        (__attribute__((address_space(3))) unsigned int*)l,
        16, 0, 0);
}

// ---------------------------------------------------------------------------
// Fused prep kernel:
//  blocks 0..255   : hxb[i][h] = x·W1x^T + b1 / hyv[j][h] = y·W1y^T
//  blocks 256..383 : W2 f32 -> bf16 step-major fragment layout:
//     w2s[s 16][c 32][lane 64][8], elem = W2[c*16 + (l&15)][s*32 + (l>>4)*8 + j]
//  (step-major so one h-step's 32KB is contiguous for global_load_lds staging)
// ---------------------------------------------------------------------------
__global__ __launch_bounds__(256) void prep_fused(
    const float* __restrict__ x, const float* __restrict__ y,
    const float* __restrict__ W1, const float* __restrict__ b1,
    const float* __restrict__ W2,
    float* __restrict__ hxb, float* __restrict__ hyv,
    unsigned short* __restrict__ w2s)
{
    const int bid = blockIdx.x;
    const int t = threadIdx.x;

    if (bid >= 256) {
        const int T = (bid - 256) * 256 + t;        // 0 .. 32767
        const int l = T & 63;
        const int c = (T >> 6) & 31;
        const int s = T >> 11;
        const int row = c * 16 + (l & 15);
        const int col = s * 32 + (l >> 4) * 8;
        const float* p = &W2[row * Hn + col];
        const float4 v0 = *(const float4*)p;
        const float4 v1 = *(const float4*)(p + 4);
        uint4 pk;
        pk.x = pkbf(v0.x, v0.y);
        pk.y = pkbf(v0.z, v0.w);
        pk.z = pkbf(v1.x, v1.y);
        pk.w = pkbf(v1.z, v1.w);
        *(uint4*)(w2s + (size_t)T * 8) = pk;        // T*8 == ((s*32+c)*64+l)*8
        return;
    }

    // ---- first-layer GEMM: 32 i x 64 h per block, 8 outputs/thread ----
    const int which = bid >> 7;
    const int rem = bid & 127;
    const int i0 = (rem >> 3) * 32;
    const int h0 = (rem & 7) * 64;
    const float* __restrict__ src = which ? y : x;
    float* __restrict__ dst = which ? hyv : hxb;
    const int off = which ? DXn : 0;

    __shared__ float xs[32][132];
    __shared__ float ws[64][132];
    #pragma unroll
    for (int it = 0; it < 4; ++it) {
        const int fi = it * 256 + t;
        const int r = fi >> 5, q = fi & 31;
        *(float4*)&xs[r][q * 4] = *(const float4*)&src[(i0 + r) * DXn + q * 4];
    }
    #pragma unroll
    for (int it = 0; it < 8; ++it) {
        const int fi = it * 256 + t;
        const int r = fi >> 5, q = fi & 31;
        *(float4*)&ws[r][q * 4] = *(const float4*)&W1[(h0 + r) * (2 * DXn) + off + q * 4];
    }
    __syncthreads();

    const int tx = t & 15;
    const int ty = t >> 4;
    float acc[2][4];
    #pragma unroll
    for (int v = 0; v < 2; ++v)
        #pragma unroll
        for (int u = 0; u < 4; ++u)
            acc[v][u] = which ? 0.0f : b1[h0 + tx + u * 16];

    #pragma unroll 4
    for (int c4 = 0; c4 < 32; ++c4) {
        const float4 xv0 = *(const float4*)&xs[ty * 2 + 0][c4 * 4];
        const float4 xv1 = *(const float4*)&xs[ty * 2 + 1][c4 * 4];
        #pragma unroll
        for (int u = 0; u < 4; ++u) {
            const float4 wv = *(const float4*)&ws[tx + u * 16][c4 * 4];
            acc[0][u] = fmaf(xv0.x, wv.x, fmaf(xv0.y, wv.y, fmaf(xv0.z, wv.z, fmaf(xv0.w, wv.w, acc[0][u]))));
            acc[1][u] = fmaf(xv1.x, wv.x, fmaf(xv1.y, wv.y, fmaf(xv1.z, wv.z, fmaf(xv1.w, wv.w, acc[1][u]))));
        }
    }
    #pragma unroll
    for (int v = 0; v < 2; ++v)
        #pragma unroll
        for (int u = 0; u < 4; ++u)
            dst[(size_t)(i0 + ty * 2 + v) * Hn + h0 + tx + u * 16] = acc[v][u];
}

// generate one A half-tile (128 rows x 256 h, bf16, fragment-ordered) into LDS
static __device__ __forceinline__ void gen_a_half(
    unsigned short* a_us, const float* __restrict__ hyrow,
    const float* __restrict__ hxrow, int p, int w, int l, int lg)
{
    #pragma unroll
    for (int q = 0; q < 8; ++q) {
        const int h0 = (p * 8 + q) * 32 + lg * 8;
        const float4 a0 = *(const float4*)(hyrow + h0);
        const float4 a1 = *(const float4*)(hyrow + h0 + 4);
        const float4 x0 = *(const float4*)(hxrow + h0);
        const float4 x1 = *(const float4*)(hxrow + h0 + 4);
        uint4 pk;
        pk.x = pkbf(fmaxf(a0.x + x0.x, 0.f), fmaxf(a0.y + x0.y, 0.f));
        pk.y = pkbf(fmaxf(a0.z + x0.z, 0.f), fmaxf(a0.w + x0.w, 0.f));
        pk.z = pkbf(fmaxf(a1.x + x1.x, 0.f), fmaxf(a1.y + x1.y, 0.f));
        pk.w = pkbf(fmaxf(a1.z + x1.z, 0.f), fmaxf(a1.w + x1.w, 0.f));
        *(uint4*)(a_us + ((size_t)(w * 8 + q) * 64 + l) * 8) = pk;
    }
}

// ---------------------------------------------------------------------------
// Main fused kernel, 2-phase interleaved schedule (T3-minimum).
// Block = (one i, 128 j's), 8 waves, wave-tile 128x64 (fi=8, fj=4), 16x16x32.
// LDS: A half-tile [8 fi][8 q][64 l][16B] = 64KB (regenerated at h=256)
//      B dbuf     [2][32 c][64 l][16B]    = 64KB, staged via global_load_lds.
// Per step: issue B(s+1) stage -> ds_read a[8],b[4] -> setprio MFMA x32 ->
//           __syncthreads (drains stage; MFMA burst covered the L2 flight).
// ---------------------------------------------------------------------------
__global__ __launch_bounds__(512, 2) void critic_main(
    const float* __restrict__ hxb, const float* __restrict__ hyv,
    const unsigned short* __restrict__ w2s, const float* __restrict__ b2,
    const float* __restrict__ W3, const float* __restrict__ b3,
    float* __restrict__ out)
{
    __shared__ __align__(16) unsigned char smem[131072];
    unsigned short* a_us = (unsigned short*)smem;   // 64KB A half-tile
    unsigned char* b_base = smem + 65536;           // 64KB B double-buffer
    float* red = (float*)smem;                      // epilogue reuse

    const int i   = blockIdx.y;
    const int j0  = blockIdx.x * 128;
    const int tid = threadIdx.x;
    const int w   = tid >> 6;
    const int l   = tid & 63;
    const int lg  = l >> 4;
    const int lm  = l & 15;

    const float* __restrict__ hxrow = &hxb[(size_t)i * Hn];
    const int r = w * 16 + lm;
    const float* __restrict__ hyrow = &hyv[(size_t)(j0 + r) * Hn];
    const unsigned char* __restrict__ w2b = (const unsigned char*)w2s;

    // ---- prologue: stage B step 0, generate A half 0 ----
    #pragma unroll
    for (int n = 0; n < 4; ++n) {
        const int c = w * 4 + n;
        gld_lds16(w2b + (size_t)c * 1024 + l * 16, b_base + c * 1024);
    }
    gen_a_half(a_us, hyrow, hxrow, 0, w, l, lg);
    __syncthreads();

    f32x4 acc[8][4] = {};

    #pragma unroll
    for (int p = 0; p < 2; ++p) {
        if (p == 1) {
            gen_a_half(a_us, hyrow, hxrow, 1, w, l, lg);
            __syncthreads();
        }
        #pragma unroll
        for (int q = 0; q < 8; ++q) {
            const int s = p * 8 + q;
            // issue next-step B staging FIRST (flight covered by MFMA burst)
            if (s < 15) {
                const int sn = s + 1;
                const int nb = sn & 1;
                #pragma unroll
                for (int n = 0; n < 4; ++n) {
                    const int c = w * 4 + n;
                    gld_lds16(w2b + (size_t)sn * 32768 + c * 1024 + l * 16,
                              b_base + nb * 32768 + c * 1024);
                }
            }
            const int cb = s & 1;
            bf16x8 a[8], b[4];
            #pragma unroll
            for (int fj = 0; fj < 4; ++fj)
                b[fj] = *(const bf16x8*)(b_base + cb * 32768 + (w * 4 + fj) * 1024 + l * 16);
            #pragma unroll
            for (int fi = 0; fi < 8; ++fi)
                a[fi] = *(const bf16x8*)(a_us + ((size_t)(fi * 8 + q) * 64 + l) * 8);
            __builtin_amdgcn_s_setprio(1);
            #pragma unroll
            for (int fi = 0; fi < 8; ++fi)
                #pragma unroll
                for (int fj = 0; fj < 4; ++fj)
                    acc[fi][fj] = __builtin_amdgcn_mfma_f32_16x16x32_bf16(
                        a[fi], b[fj], acc[fi][fj], 0, 0, 0);
            __builtin_amdgcn_s_setprio(0);
            __syncthreads();
        }
    }

    // ---- epilogue: relu(C + b2)*W3, reduce over k (same as round-3) ----
    float b2v[4], w3v[4];
    #pragma unroll
    for (int fj = 0; fj < 4; ++fj) {
        const int k = w * 64 + fj * 16 + lm;
        b2v[fj] = b2[k];
        w3v[fj] = W3[k];
    }
    float rp[8][4];
    #pragma unroll
    for (int fi = 0; fi < 8; ++fi) {
        #pragma unroll
        for (int qq = 0; qq < 4; ++qq) {
            float ssum = 0.f;
            #pragma unroll
            for (int fj = 0; fj < 4; ++fj) {
                float c = acc[fi][fj][qq] + b2v[fj];
                c = fmaxf(c, 0.f);
                ssum = fmaf(c, w3v[fj], ssum);
            }
            rp[fi][qq] = ssum;
        }
    }
    #pragma unroll
    for (int m = 1; m < 16; m <<= 1) {
        #pragma unroll
        for (int fi = 0; fi < 8; ++fi)
            #pragma unroll
            for (int qq = 0; qq < 4; ++qq)
                rp[fi][qq] += __shfl_xor(rp[fi][qq], m, 64);
    }

    // last __syncthreads of the K-loop already separates a_us reads from red
    if (lm == 0) {
        #pragma unroll
        for (int fi = 0; fi < 8; ++fi)
            #pragma unroll
            for (int qq = 0; qq < 4; ++qq)
                red[w * 128 + fi * 16 + lg * 4 + qq] = rp[fi][qq];
    }
    __syncthreads();
    if (tid < 128) {
        float ssum = 0.f;
        #pragma unroll
        for (int ww = 0; ww < 8; ++ww) ssum += red[ww * 128 + tid];
        out[(size_t)i * Bn + j0 + tid] = ssum + b3[0];
    }
}

// ---------------------------------------------------------------------------
extern "C" void kernel_launch(void* const* d_in, const int* in_sizes, int n_in,
                              void* d_out, int out_size, void* d_ws, size_t ws_size,
                              hipStream_t stream) {
    const float* x  = (const float*)d_in[0];
    const float* y  = (const float*)d_in[1];
    const float* W1 = (const float*)d_in[2];
    const float* b1 = (const float*)d_in[3];
    const float* W2 = (const float*)d_in[4];
    const float* b2 = (const float*)d_in[5];
    const float* W3 = (const float*)d_in[6];
    const float* b3 = (const float*)d_in[7];
    float* out = (float*)d_out;

    char* ws = (char*)d_ws;
    float* hxb = (float*)ws;                                   // 1 MB
    float* hyv = (float*)(ws + (size_t)Bn * Hn * 4);           // 1 MB
    unsigned short* w2s = (unsigned short*)(ws + (size_t)2 * Bn * Hn * 4); // 512 KB

    prep_fused<<<dim3(384), dim3(256), 0, stream>>>(x, y, W1, b1, W2, hxb, hyv, w2s);
    critic_main<<<dim3(Bn / 128, Bn), dim3(512), 0, stream>>>(hxb, hyv, w2s, b2, W3, b3, out);
}

// Round 6
// 252.626 us; speedup vs baseline: 1.1100x; 1.0419x over previous
//
#include <hip/hip_runtime.h>
#include <hip/hip_bf16.h>

#define Bn  512
#define DXn 128
#define Hn  512

using bf16x8 = __attribute__((ext_vector_type(8))) short;
using f32x4  = __attribute__((ext_vector_type(4))) float;

#define VMCNT(n) asm volatile("s_waitcnt vmcnt(" #n ")" ::: "memory")

// packed f32x2 -> bf16x2 (RNE); compiler emits v_cvt_pk_bf16_f32
static __device__ __forceinline__ unsigned int pkbf(float lo, float hi) {
    union { __hip_bfloat162 b; unsigned int u; } cv;
    cv.b = __float22bfloat162_rn(make_float2(lo, hi));
    return cv.u;
}

// async global->LDS, 16B per lane; LDS dest = wave-uniform base + lane*16
static __device__ __forceinline__ void gld_lds16(const void* g, void* l) {
    __builtin_amdgcn_global_load_lds(
        (const __attribute__((address_space(1))) unsigned int*)g,
        (__attribute__((address_space(3))) unsigned int*)l,
        16, 0, 0);
}

// ---------------------------------------------------------------------------
// Fused prep kernel:
//  blocks 0..255   : hxb[i][h] = x·W1x^T + b1 / hyv[j][h] = y·W1y^T
//  blocks 256..383 : W2 f32 -> bf16 step-major fragment layout:
//     w2s[s 16][c 32][lane 64][8], elem = W2[c*16 + (l&15)][s*32 + (l>>4)*8 + j]
// ---------------------------------------------------------------------------
__global__ __launch_bounds__(256) void prep_fused(
    const float* __restrict__ x, const float* __restrict__ y,
    const float* __restrict__ W1, const float* __restrict__ b1,
    const float* __restrict__ W2,
    float* __restrict__ hxb, float* __restrict__ hyv,
    unsigned short* __restrict__ w2s)
{
    const int bid = blockIdx.x;
    const int t = threadIdx.x;

    if (bid >= 256) {
        const int T = (bid - 256) * 256 + t;        // 0 .. 32767
        const int l = T & 63;
        const int c = (T >> 6) & 31;
        const int s = T >> 11;
        const int row = c * 16 + (l & 15);
        const int col = s * 32 + (l >> 4) * 8;
        const float* p = &W2[row * Hn + col];
        const float4 v0 = *(const float4*)p;
        const float4 v1 = *(const float4*)(p + 4);
        uint4 pk;
        pk.x = pkbf(v0.x, v0.y);
        pk.y = pkbf(v0.z, v0.w);
        pk.z = pkbf(v1.x, v1.y);
        pk.w = pkbf(v1.z, v1.w);
        *(uint4*)(w2s + (size_t)T * 8) = pk;        // T*8 == ((s*32+c)*64+l)*8
        return;
    }

    // ---- first-layer GEMM: 32 i x 64 h per block, 8 outputs/thread ----
    const int which = bid >> 7;
    const int rem = bid & 127;
    const int i0 = (rem >> 3) * 32;
    const int h0 = (rem & 7) * 64;
    const float* __restrict__ src = which ? y : x;
    float* __restrict__ dst = which ? hyv : hxb;
    const int off = which ? DXn : 0;

    __shared__ float xs[32][132];
    __shared__ float ws[64][132];
    #pragma unroll
    for (int it = 0; it < 4; ++it) {
        const int fi = it * 256 + t;
        const int r = fi >> 5, q = fi & 31;
        *(float4*)&xs[r][q * 4] = *(const float4*)&src[(i0 + r) * DXn + q * 4];
    }
    #pragma unroll
    for (int it = 0; it < 8; ++it) {
        const int fi = it * 256 + t;
        const int r = fi >> 5, q = fi & 31;
        *(float4*)&ws[r][q * 4] = *(const float4*)&W1[(h0 + r) * (2 * DXn) + off + q * 4];
    }
    __syncthreads();

    const int tx = t & 15;
    const int ty = t >> 4;
    float acc[2][4];
    #pragma unroll
    for (int v = 0; v < 2; ++v)
        #pragma unroll
        for (int u = 0; u < 4; ++u)
            acc[v][u] = which ? 0.0f : b1[h0 + tx + u * 16];

    #pragma unroll 4
    for (int c4 = 0; c4 < 32; ++c4) {
        const float4 xv0 = *(const float4*)&xs[ty * 2 + 0][c4 * 4];
        const float4 xv1 = *(const float4*)&xs[ty * 2 + 1][c4 * 4];
        #pragma unroll
        for (int u = 0; u < 4; ++u) {
            const float4 wv = *(const float4*)&ws[tx + u * 16][c4 * 4];
            acc[0][u] = fmaf(xv0.x, wv.x, fmaf(xv0.y, wv.y, fmaf(xv0.z, wv.z, fmaf(xv0.w, wv.w, acc[0][u]))));
            acc[1][u] = fmaf(xv1.x, wv.x, fmaf(xv1.y, wv.y, fmaf(xv1.z, wv.z, fmaf(xv1.w, wv.w, acc[1][u]))));
        }
    }
    #pragma unroll
    for (int v = 0; v < 2; ++v)
        #pragma unroll
        for (int u = 0; u < 4; ++u)
            dst[(size_t)(i0 + ty * 2 + v) * Hn + h0 + tx + u * 16] = acc[v][u];
}

// generate one A half-tile (128 rows x 256 h, bf16, fragment-ordered) into LDS
static __device__ __forceinline__ void gen_a_half(
    unsigned short* a_us, const float* __restrict__ hyrow,
    const float* __restrict__ hxrow, int p, int w, int l, int lg)
{
    #pragma unroll
    for (int q = 0; q < 8; ++q) {
        const int h0 = (p * 8 + q) * 32 + lg * 8;
        const float4 a0 = *(const float4*)(hyrow + h0);
        const float4 a1 = *(const float4*)(hyrow + h0 + 4);
        const float4 x0 = *(const float4*)(hxrow + h0);
        const float4 x1 = *(const float4*)(hxrow + h0 + 4);
        uint4 pk;
        pk.x = pkbf(fmaxf(a0.x + x0.x, 0.f), fmaxf(a0.y + x0.y, 0.f));
        pk.y = pkbf(fmaxf(a0.z + x0.z, 0.f), fmaxf(a0.w + x0.w, 0.f));
        pk.z = pkbf(fmaxf(a1.x + x1.x, 0.f), fmaxf(a1.y + x1.y, 0.f));
        pk.w = pkbf(fmaxf(a1.z + x1.z, 0.f), fmaxf(a1.w + x1.w, 0.f));
        *(uint4*)(a_us + ((size_t)(w * 8 + q) * 64 + l) * 8) = pk;
    }
}

// ---------------------------------------------------------------------------
// Main fused kernel, counted-vmcnt schedule (T3+T4; no per-step barriers).
// Block = (one i, 128 j's), 8 waves, wave-tile 128x64 (fi=8, fj=4), 16x16x32.
// LDS: A half-tile 64KB (regenerated at h=256, the ONLY cross-wave dep)
//      B dbuf 2x32KB via global_load_lds; each wave stages AND consumes only
//      its own 4KB chunk per step -> B needs no barriers, only per-wave vmcnt.
// Steady state per step s: issue stage(s+1) [4 gld_lds] -> outstanding 8 ->
//   s_waitcnt vmcnt(4) retires stage-s (in-order) -> ds_read b[4],a[8] ->
//   setprio(1) 32xMFMA setprio(0).  Step 15 waits vmcnt(0).
// Block-wide barriers: 1 post-prologue + 2 around A-regen + epilogue only.
// ---------------------------------------------------------------------------
__global__ __launch_bounds__(512, 2) void critic_main(
    const float* __restrict__ hxb, const float* __restrict__ hyv,
    const unsigned short* __restrict__ w2s, const float* __restrict__ b2,
    const float* __restrict__ W3, const float* __restrict__ b3,
    float* __restrict__ out)
{
    __shared__ __align__(16) unsigned char smem[131072];
    unsigned short* a_us = (unsigned short*)smem;   // 64KB A half-tile
    unsigned char* b_base = smem + 65536;           // 64KB B double-buffer
    float* red = (float*)smem;                      // epilogue reuse

    const int i   = blockIdx.y;
    const int j0  = blockIdx.x * 128;
    const int tid = threadIdx.x;
    const int w   = tid >> 6;
    const int l   = tid & 63;
    const int lg  = l >> 4;
    const int lm  = l & 15;

    const float* __restrict__ hxrow = &hxb[(size_t)i * Hn];
    const int r = w * 16 + lm;
    const float* __restrict__ hyrow = &hyv[(size_t)(j0 + r) * Hn];
    const unsigned char* __restrict__ w2b = (const unsigned char*)w2s;

    // ---- prologue: stage B step 0, generate A half 0 ----
    #pragma unroll
    for (int n = 0; n < 4; ++n) {
        const int c = w * 4 + n;
        gld_lds16(w2b + (size_t)c * 1024 + l * 16, b_base + c * 1024);
    }
    gen_a_half(a_us, hyrow, hxrow, 0, w, l, lg);
    __syncthreads();   // A half 0 visible; drains stage-0 too

    f32x4 acc[8][4] = {};

    #pragma unroll
    for (int p = 0; p < 2; ++p) {
        if (p == 1) {
            __syncthreads();   // all waves done reading A half 0
            gen_a_half(a_us, hyrow, hxrow, 1, w, l, lg);
            __syncthreads();   // A half 1 visible (drains in-flight stage too)
        }
        #pragma unroll
        for (int q = 0; q < 8; ++q) {
            const int s = p * 8 + q;
            // issue next-step B staging FIRST (stays in flight across the wait)
            if (s < 15) {
                const int sn = s + 1;
                const int nb = sn & 1;
                #pragma unroll
                for (int n = 0; n < 4; ++n) {
                    const int c = w * 4 + n;
                    gld_lds16(w2b + (size_t)sn * 32768 + c * 1024 + l * 16,
                              b_base + nb * 32768 + c * 1024);
                }
            }
            // counted wait: retire stage-s (oldest 4), keep stage-(s+1) flying
            if (s < 15) { VMCNT(4); } else { VMCNT(0); }

            const int cb = s & 1;
            bf16x8 a[8], b[4];
            #pragma unroll
            for (int fj = 0; fj < 4; ++fj)
                b[fj] = *(const bf16x8*)(b_base + cb * 32768 + (w * 4 + fj) * 1024 + l * 16);
            #pragma unroll
            for (int fi = 0; fi < 8; ++fi)
                a[fi] = *(const bf16x8*)(a_us + ((size_t)(fi * 8 + q) * 64 + l) * 8);
            __builtin_amdgcn_s_setprio(1);
            #pragma unroll
            for (int fi = 0; fi < 8; ++fi)
                #pragma unroll
                for (int fj = 0; fj < 4; ++fj)
                    acc[fi][fj] = __builtin_amdgcn_mfma_f32_16x16x32_bf16(
                        a[fi], b[fj], acc[fi][fj], 0, 0, 0);
            __builtin_amdgcn_s_setprio(0);
        }
    }

    // ---- epilogue: relu(C + b2)*W3, reduce over k ----
    float b2v[4], w3v[4];
    #pragma unroll
    for (int fj = 0; fj < 4; ++fj) {
        const int k = w * 64 + fj * 16 + lm;
        b2v[fj] = b2[k];
        w3v[fj] = W3[k];
    }
    float rp[8][4];
    #pragma unroll
    for (int fi = 0; fi < 8; ++fi) {
        #pragma unroll
        for (int qq = 0; qq < 4; ++qq) {
            float ssum = 0.f;
            #pragma unroll
            for (int fj = 0; fj < 4; ++fj) {
                float c = acc[fi][fj][qq] + b2v[fj];
                c = fmaxf(c, 0.f);
                ssum = fmaf(c, w3v[fj], ssum);
            }
            rp[fi][qq] = ssum;
        }
    }
    #pragma unroll
    for (int m = 1; m < 16; m <<= 1) {
        #pragma unroll
        for (int fi = 0; fi < 8; ++fi)
            #pragma unroll
            for (int qq = 0; qq < 4; ++qq)
                rp[fi][qq] += __shfl_xor(rp[fi][qq], m, 64);
    }

    __syncthreads();   // all waves done with a_us; safe to reuse as red[]
    if (lm == 0) {
        #pragma unroll
        for (int fi = 0; fi < 8; ++fi)
            #pragma unroll
            for (int qq = 0; qq < 4; ++qq)
                red[w * 128 + fi * 16 + lg * 4 + qq] = rp[fi][qq];
    }
    __syncthreads();
    if (tid < 128) {
        float ssum = 0.f;
        #pragma unroll
        for (int ww = 0; ww < 8; ++ww) ssum += red[ww * 128 + tid];
        out[(size_t)i * Bn + j0 + tid] = ssum + b3[0];
    }
}

// ---------------------------------------------------------------------------
extern "C" void kernel_launch(void* const* d_in, const int* in_sizes, int n_in,
                              void* d_out, int out_size, void* d_ws, size_t ws_size,
                              hipStream_t stream) {
    const float* x  = (const float*)d_in[0];
    const float* y  = (const float*)d_in[1];
    const float* W1 = (const float*)d_in[2];
    const float* b1 = (const float*)d_in[3];
    const float* W2 = (const float*)d_in[4];
    const float* b2 = (const float*)d_in[5];
    const float* W3 = (const float*)d_in[6];
    const float* b3 = (const float*)d_in[7];
    float* out = (float*)d_out;

    char* ws = (char*)d_ws;
    float* hxb = (float*)ws;                                   // 1 MB
    float* hyv = (float*)(ws + (size_t)Bn * Hn * 4);           // 1 MB
    unsigned short* w2s = (unsigned short*)(ws + (size_t)2 * Bn * Hn * 4); // 512 KB

    prep_fused<<<dim3(384), dim3(256), 0, stream>>>(x, y, W1, b1, W2, hxb, hyv, w2s);
    critic_main<<<dim3(Bn / 128, Bn), dim3(512), 0, stream>>>(hxb, hyv, w2s, b2, W3, b3, out);
}